// Round 5
// baseline (295.171 us; speedup 1.0000x reference)
//
#include <hip/hip_runtime.h>

// ---------------------------------------------------------------------------
// MLPDeepSet fused fp16-MFMA implementation for gfx950.
//
//  k_prep : convert x->fp16, prepack all weights into MFMA A-fragment order
//           (fp16), init d_out = b_out.
//  k_atoms: AP = x @ W_in[0:256] + b_in ; BP = x @ W_in[256:512]  (fp16 out)
//  k_edges: per 64-edge block (2 blocks/CU): h0 = rbf/d MFMA + AP[i]+BP[j];
//           6 fused 256x256 layers (fp16 MFMA, f32 acc, fast SiLU after
//           first 5) with DOUBLE-BUFFERED h in LDS -> 1 barrier/layer and
//           epilogue-VALU overlaps other waves' MFMA; per-edge dot with
//           W_out; block reduce; atomicAdd into d_out.
//  R5: 64-edge blocks, 8 waves x 32-feature slices (no duplicate weight
//      loads), h dbuf (65 KB LDS, 2 blocks/CU), 1 barrier/layer.
// ---------------------------------------------------------------------------

typedef _Float16 f16x8 __attribute__((ext_vector_type(8)));
typedef _Float16 f16x4 __attribute__((ext_vector_type(4)));
typedef __fp16   fp16v2 __attribute__((ext_vector_type(2)));
typedef float    f32x4 __attribute__((ext_vector_type(4)));
typedef unsigned int u32x4 __attribute__((ext_vector_type(4)));
typedef unsigned int u32x2 __attribute__((ext_vector_type(2)));

union H8 { f16x8 v; _Float16 h[8]; u32x4 u; };
union H4 { f16x4 v; u32x2 u; };
union H2 { fp16v2 h; unsigned int u; };

#define MFMA16(a, b, c) __builtin_amdgcn_mfma_f32_16x16x32_f16((a), (b), (c), 0, 0, 0)

#define LOG2E 1.44269504088896340736f

// workspace byte offsets
#define WS_WP   0u          // 6 layers  : 6*65536 halves = 786432 B
#define WS_WPI  786432u     // 65536 halves = 131072 B
#define WS_WPJ  917504u     // 65536 halves = 131072 B
#define WS_WPR  1048576u    // 8192 halves  = 16384 B   (rbf+d, K padded to 32)
#define WS_XH   1064960u    // 2097152 halves = 4194304 B
#define WS_AP   5259264u    // 2097152 fp16 = 4194304 B
#define WS_BP   9453568u    // 2097152 fp16 = 4194304 B
// total 13647872 B

// ---------------------------------------------------------------------------
__global__ __launch_bounds__(256) void k_prep(
    const float* __restrict__ x, const float* __restrict__ W_in,
    const float* __restrict__ Ws, const float* __restrict__ b_out,
    _Float16* __restrict__ wp, _Float16* __restrict__ wpi,
    _Float16* __restrict__ wpj, _Float16* __restrict__ wpr,
    _Float16* __restrict__ xh, float* __restrict__ out)
{
  int i = blockIdx.x * 256 + threadIdx.x;
  if (i < 2097152) { xh[i] = (_Float16)x[i]; return; }
  i -= 2097152;
  if (i < 393216) {  // 6 hidden layers, A-fragment order (A = W^T)
    int m = i >> 16, r = i & 65535;
    int j = r & 7, lane = (r >> 3) & 63, ks = (r >> 9) & 7, nt = (r >> 12) & 15;
    int k = ks * 32 + (lane >> 4) * 8 + j, n = nt * 16 + (lane & 15);
    wp[i] = (_Float16)Ws[(m * 256 + k) * 256 + n];
    return;
  }
  i -= 393216;
  if (i < 65536) {   // W_in rows 0..255 (x_i part)
    int j = i & 7, lane = (i >> 3) & 63, ks = (i >> 9) & 7, nt = (i >> 12) & 15;
    int k = ks * 32 + (lane >> 4) * 8 + j, n = nt * 16 + (lane & 15);
    wpi[i] = (_Float16)W_in[k * 256 + n];
    return;
  }
  i -= 65536;
  if (i < 65536) {   // W_in rows 256..511 (x_j part)
    int j = i & 7, lane = (i >> 3) & 63, ks = (i >> 9) & 7, nt = (i >> 12) & 15;
    int k = ks * 32 + (lane >> 4) * 8 + j, n = nt * 16 + (lane & 15);
    wpj[i] = (_Float16)W_in[(256 + k) * 256 + n];
    return;
  }
  i -= 65536;
  if (i < 8192) {    // rbf rows 512..531 + d row 532, K padded 20+1 -> 32
    int j = i & 7, lane = (i >> 3) & 63, nt = (i >> 9) & 15;
    int k = (lane >> 4) * 8 + j, n = nt * 16 + (lane & 15);
    float v = 0.0f;
    if (k < 20)       v = W_in[(512 + k) * 256 + n];
    else if (k == 20) v = W_in[532 * 256 + n];
    wpr[i] = (_Float16)v;
    return;
  }
  i -= 8192;
  if (i < 8192) out[i] = b_out[0];
}

// ---------------------------------------------------------------------------
// AP/BP: M=8192 atoms, K=256, N=256, fp16 packed output. BM=64 atoms/block,
// 4 waves (one 64-n slice each). blockIdx.y selects AP (with b_in) or BP.
__global__ __launch_bounds__(256) void k_atoms(
    const _Float16* __restrict__ xh,
    const _Float16* __restrict__ wpi, const _Float16* __restrict__ wpj,
    const float* __restrict__ b_in,
    _Float16* __restrict__ AP, _Float16* __restrict__ BP)
{
  const int tid = threadIdx.x;
  const int l = tid & 63, w = tid >> 6;
  const int g = l >> 4, c = l & 15;
  const int which = blockIdx.y;
  const _Float16* wpx = which ? wpj : wpi;
  _Float16* outp = which ? BP : AP;
  const int abase = blockIdx.x * 64;

  f32x4 acc[4][4];
#pragma unroll
  for (int nf = 0; nf < 4; ++nf)
#pragma unroll
    for (int at = 0; at < 4; ++at) acc[nf][at] = (f32x4)0.0f;

#pragma unroll
  for (int ks = 0; ks < 8; ++ks) {
    f16x8 a[4];
#pragma unroll
    for (int nf = 0; nf < 4; ++nf) {
      H8 t; t.u = *(const u32x4*)(wpx + (((w * 4 + nf) * 8 + ks) * 64 + l) * 8);
      a[nf] = t.v;
    }
#pragma unroll
    for (int at = 0; at < 4; ++at) {
      H8 b; b.u = *(const u32x4*)(xh + (abase + at * 16 + c) * 256 + ks * 32 + g * 8);
#pragma unroll
      for (int nf = 0; nf < 4; ++nf)
        acc[nf][at] = MFMA16(a[nf], b.v, acc[nf][at]);
    }
  }

#pragma unroll
  for (int nf = 0; nf < 4; ++nf) {
    const int n = w * 64 + nf * 16 + g * 4;
    f32x4 bias = (f32x4)0.0f;
    if (!which) bias = *(const f32x4*)(b_in + n);
#pragma unroll
    for (int at = 0; at < 4; ++at) {
      const int atom = abase + at * 16 + c;
      const f32x4 t = acc[nf][at] + bias;
      H2 lo, hi;
      lo.h = __builtin_amdgcn_cvt_pkrtz(t[0], t[1]);
      hi.h = __builtin_amdgcn_cvt_pkrtz(t[2], t[3]);
      u32x2 q; q[0] = lo.u; q[1] = hi.u;
      *(u32x2*)(outp + atom * 256 + n) = q;
    }
  }
}

// ---------------------------------------------------------------------------
// Fused edge pipeline. 64 edges/block, 512 threads = 8 waves, wave w owns
// features [w*32, w*32+32). h tile [64 edges][256 feat] fp16, DOUBLE-BUFFERED
// in LDS (32 KB each). Row swizzle: addr = el*512 + (o ^ sw),
// sw = (c<<4)|((c&1)<<8). One barrier per layer.
__global__ __launch_bounds__(512, 4) void k_edges(
    const _Float16* __restrict__ AP, const _Float16* __restrict__ BP,
    const int* __restrict__ idx_i, const int* __restrict__ idx_j,
    const float* __restrict__ d_ij,
    const _Float16* __restrict__ wp, const _Float16* __restrict__ wpr,
    const float* __restrict__ bs, const float* __restrict__ W_out,
    float* __restrict__ out)
{
  __shared__ __align__(16) char hb[2][32768];
  __shared__ float d_lds[64];
  __shared__ int   ii_lds[64];
  __shared__ int   jj_lds[64];
  __shared__ float oacc[64];

  const int tid = threadIdx.x;
  const int l = tid & 63, w = tid >> 6;
  const int g = l >> 4, c = l & 15;
  const int ebase = blockIdx.x * 64;
  const int nb = w * 32;          // wave's feature base (32 features)
  const int sw = (c << 4) | ((c & 1) << 8);  // row swizzle

  if (tid < 64) {
    ii_lds[tid] = idx_i[ebase + tid];
    jj_lds[tid] = idx_j[ebase + tid];
    d_lds[tid]  = d_ij[ebase + tid];
    oacc[tid]   = 0.0f;
  }
  __syncthreads();

  f32x4 acc[2][4];  // [nf][et] : D = h^T tile (features x edges)

  // ---- input layer: rbf(20)+d via one K=32 MFMA step ----
  {
    const float STEP = 15.0f / 19.0f;
    const float C2 = (-0.5f / (STEP * STEP)) * LOG2E;
    f16x8 afr[2];
#pragma unroll
    for (int nf = 0; nf < 2; ++nf) {
      H8 t; t.u = *(const u32x4*)(wpr + ((w * 2 + nf) * 64 + l) * 8);
      afr[nf] = t.v;
    }
#pragma unroll
    for (int et = 0; et < 4; ++et) {
      const float d = d_lds[et * 16 + c];
      H8 bb;
#pragma unroll
      for (int j = 0; j < 8; ++j) {
        const int k = g * 8 + j;
        float v = 0.0f;
        if (k < 20)       { const float df = d - (float)k * STEP; v = __builtin_amdgcn_exp2f(C2 * df * df); }
        else if (k == 20) { v = d; }
        bb.h[j] = (_Float16)v;
      }
      const f32x4 z = (f32x4)0.0f;
#pragma unroll
      for (int nf = 0; nf < 2; ++nf)
        acc[nf][et] = MFMA16(afr[nf], bb.v, z);
    }
  }
  // h0 = pack(rbf acc) + AP[idx_i] + BP[idx_j]  (fp16 pk_add) -> hb[0]
#pragma unroll
  for (int nf = 0; nf < 2; ++nf) {
    const int n = nb + nf * 16 + g * 4;
    const int obase = n * 2;
#pragma unroll
    for (int et = 0; et < 4; ++et) {
      const int el = et * 16 + c;
      H4 pa, pb, s;
      pa.u = *(const u32x2*)(AP + ii_lds[el] * 256 + n);
      pb.u = *(const u32x2*)(BP + jj_lds[el] * 256 + n);
      H2 lo, hi;
      lo.h = __builtin_amdgcn_cvt_pkrtz(acc[nf][et][0], acc[nf][et][1]);
      hi.h = __builtin_amdgcn_cvt_pkrtz(acc[nf][et][2], acc[nf][et][3]);
      s.u[0] = lo.u; s.u[1] = hi.u;
      s.v = s.v + pa.v + pb.v;
      *(u32x2*)(hb[0] + el * 512 + (obase ^ sw)) = s.u;
    }
  }
  __syncthreads();

  int cur = 0;

  // one fused hidden-layer matmul: acc = bias + (h_lds[cur] @ W)^T
  auto mfma_layer = [&](const _Float16* wl, const float* brow) {
#pragma unroll
    for (int nf = 0; nf < 2; ++nf) {
      const f32x4 bias = *(const f32x4*)(brow + nb + nf * 16 + g * 4);
#pragma unroll
      for (int et = 0; et < 4; ++et) acc[nf][et] = bias;
    }
    __builtin_amdgcn_s_setprio(1);
#pragma unroll
    for (int ks = 0; ks < 8; ++ks) {
      f16x8 a[2];
#pragma unroll
      for (int nf = 0; nf < 2; ++nf) {
        H8 t; t.u = *(const u32x4*)(wl + (((w * 2 + nf) * 8 + ks) * 64 + l) * 8);
        a[nf] = t.v;
      }
      const int o = (ks * 64 + g * 16) ^ sw;
#pragma unroll
      for (int et = 0; et < 4; ++et) {
        const int el = et * 16 + c;
        H8 b; b.u = *(const u32x4*)(hb[cur] + el * 512 + o);
#pragma unroll
        for (int nf = 0; nf < 2; ++nf)
          acc[nf][et] = MFMA16(a[nf], b.v, acc[nf][et]);
      }
    }
    __builtin_amdgcn_s_setprio(0);
  };

#pragma unroll 1
  for (int ly = 0; ly < 5; ++ly) {
    mfma_layer(wp + ly * 65536, bs + ly * 256);
    // epilogue writes the OTHER buffer -> no barrier needed before it
#pragma unroll
    for (int nf = 0; nf < 2; ++nf) {
      const int n = nb + nf * 16 + g * 4;
      const int obase = n * 2;
#pragma unroll
      for (int et = 0; et < 4; ++et) {
        f32x4 v = acc[nf][et];
#pragma unroll
        for (int j = 0; j < 4; ++j) {
          const float e = __builtin_amdgcn_exp2f(v[j] * -LOG2E);
          v[j] = v[j] * __builtin_amdgcn_rcpf(1.0f + e);   // fast SiLU
        }
        const int el = et * 16 + c;
        H2 lo, hi;
        lo.h = __builtin_amdgcn_cvt_pkrtz(v[0], v[1]);
        hi.h = __builtin_amdgcn_cvt_pkrtz(v[2], v[3]);
        u32x2 q; q[0] = lo.u; q[1] = hi.u;
        *(u32x2*)(hb[cur ^ 1] + el * 512 + (obase ^ sw)) = q;
      }
    }
    __syncthreads();   // writes to cur^1 complete before next layer reads it
    cur ^= 1;
  }

  // layer 6 (no activation): bias already seeded; fold W_out dot immediately
  mfma_layer(wp + 5 * 65536, bs + 5 * 256);
  float sum[4];
#pragma unroll
  for (int et = 0; et < 4; ++et) sum[et] = 0.0f;
#pragma unroll
  for (int nf = 0; nf < 2; ++nf) {
    const int n = nb + nf * 16 + g * 4;
    const f32x4 wo = *(const f32x4*)(W_out + n);
#pragma unroll
    for (int et = 0; et < 4; ++et) {
      const f32x4 v = acc[nf][et];
      sum[et] += v[0] * wo[0] + v[1] * wo[1] + v[2] * wo[2] + v[3] * wo[3];
    }
  }
#pragma unroll
  for (int et = 0; et < 4; ++et) {
    float s = sum[et];
    s += __shfl_xor(s, 16, 64);
    s += __shfl_xor(s, 32, 64);
    if (l < 16) atomicAdd(&oacc[et * 16 + l], s);
  }
  __syncthreads();
  if (tid < 64) atomicAdd(out + ii_lds[tid], oacc[tid]);
}

// ---------------------------------------------------------------------------
extern "C" void kernel_launch(void* const* d_in, const int* in_sizes, int n_in,
                              void* d_out, int out_size, void* d_ws, size_t ws_size,
                              hipStream_t stream) {
  (void)in_sizes; (void)n_in; (void)out_size; (void)ws_size;
  const float* x     = (const float*)d_in[0];
  const float* d_ij  = (const float*)d_in[1];
  const int*   idx_i = (const int*)d_in[2];
  const int*   idx_j = (const int*)d_in[3];
  const float* W_in  = (const float*)d_in[4];
  const float* b_in  = (const float*)d_in[5];
  const float* Ws    = (const float*)d_in[6];
  const float* bs    = (const float*)d_in[7];
  const float* W_out = (const float*)d_in[8];
  const float* b_out = (const float*)d_in[9];
  float* out = (float*)d_out;
  char* ws = (char*)d_ws;

  _Float16* wp  = (_Float16*)(ws + WS_WP);
  _Float16* wpi = (_Float16*)(ws + WS_WPI);
  _Float16* wpj = (_Float16*)(ws + WS_WPJ);
  _Float16* wpr = (_Float16*)(ws + WS_WPR);
  _Float16* xh  = (_Float16*)(ws + WS_XH);
  _Float16* AP  = (_Float16*)(ws + WS_AP);
  _Float16* BP  = (_Float16*)(ws + WS_BP);

  hipLaunchKernelGGL(k_prep, dim3(10305), dim3(256), 0, stream,
                     x, W_in, Ws, b_out, wp, wpi, wpj, wpr, xh, out);
  hipLaunchKernelGGL(k_atoms, dim3(128, 2), dim3(256), 0, stream,
                     xh, wpi, wpj, b_in, AP, BP);
  hipLaunchKernelGGL(k_edges, dim3(4096), dim3(512), 0, stream,
                     AP, BP, idx_i, idx_j, d_ij, wp, wpr, bs, W_out, out);
}

// Round 6
// 270.300 us; speedup vs baseline: 1.0920x; 1.0920x over previous
//
#include <hip/hip_runtime.h>

// ---------------------------------------------------------------------------
// MLPDeepSet fused fp16-MFMA implementation for gfx950.
//
//  k_prep : convert x->fp16, prepack all weights into MFMA A-fragment order
//           (fp16), init d_out = b_out.
//  k_atoms: AP = x @ W_in[0:256] + b_in ; BP = x @ W_in[256:512]  (fp16 out)
//  k_edges: per 128-edge block, 4 waves, wave w owns feature slice
//           [w*64, w*64+64) for ALL 128 edges (acc[4][8] = 128 AGPR) ->
//           every weight fragment loaded ONCE per block (L2 weight traffic
//           1 KB/edge/layer, half of R4). h single-buffered 64 KB in LDS,
//           2 blocks/CU for cross-block overlap during barriers.
//  R6: 64feat x 128edge wave tile; 256-thread blocks; 2 barriers/layer.
// ---------------------------------------------------------------------------

typedef _Float16 f16x8 __attribute__((ext_vector_type(8)));
typedef _Float16 f16x4 __attribute__((ext_vector_type(4)));
typedef __fp16   fp16v2 __attribute__((ext_vector_type(2)));
typedef float    f32x4 __attribute__((ext_vector_type(4)));
typedef unsigned int u32x4 __attribute__((ext_vector_type(4)));
typedef unsigned int u32x2 __attribute__((ext_vector_type(2)));

union H8 { f16x8 v; _Float16 h[8]; u32x4 u; };
union H4 { f16x4 v; u32x2 u; };
union H2 { fp16v2 h; unsigned int u; };

#define MFMA16(a, b, c) __builtin_amdgcn_mfma_f32_16x16x32_f16((a), (b), (c), 0, 0, 0)

#define LOG2E 1.44269504088896340736f

// workspace byte offsets
#define WS_WP   0u          // 6 layers  : 6*65536 halves = 786432 B
#define WS_WPI  786432u     // 65536 halves = 131072 B
#define WS_WPJ  917504u     // 65536 halves = 131072 B
#define WS_WPR  1048576u    // 8192 halves  = 16384 B   (rbf+d, K padded to 32)
#define WS_XH   1064960u    // 2097152 halves = 4194304 B
#define WS_AP   5259264u    // 2097152 fp16 = 4194304 B
#define WS_BP   9453568u    // 2097152 fp16 = 4194304 B
// total 13647872 B

// ---------------------------------------------------------------------------
__global__ __launch_bounds__(256) void k_prep(
    const float* __restrict__ x, const float* __restrict__ W_in,
    const float* __restrict__ Ws, const float* __restrict__ b_out,
    _Float16* __restrict__ wp, _Float16* __restrict__ wpi,
    _Float16* __restrict__ wpj, _Float16* __restrict__ wpr,
    _Float16* __restrict__ xh, float* __restrict__ out)
{
  int i = blockIdx.x * 256 + threadIdx.x;
  if (i < 2097152) { xh[i] = (_Float16)x[i]; return; }
  i -= 2097152;
  if (i < 393216) {  // 6 hidden layers, A-fragment order (A = W^T)
    int m = i >> 16, r = i & 65535;
    int j = r & 7, lane = (r >> 3) & 63, ks = (r >> 9) & 7, nt = (r >> 12) & 15;
    int k = ks * 32 + (lane >> 4) * 8 + j, n = nt * 16 + (lane & 15);
    wp[i] = (_Float16)Ws[(m * 256 + k) * 256 + n];
    return;
  }
  i -= 393216;
  if (i < 65536) {   // W_in rows 0..255 (x_i part)
    int j = i & 7, lane = (i >> 3) & 63, ks = (i >> 9) & 7, nt = (i >> 12) & 15;
    int k = ks * 32 + (lane >> 4) * 8 + j, n = nt * 16 + (lane & 15);
    wpi[i] = (_Float16)W_in[k * 256 + n];
    return;
  }
  i -= 65536;
  if (i < 65536) {   // W_in rows 256..511 (x_j part)
    int j = i & 7, lane = (i >> 3) & 63, ks = (i >> 9) & 7, nt = (i >> 12) & 15;
    int k = ks * 32 + (lane >> 4) * 8 + j, n = nt * 16 + (lane & 15);
    wpj[i] = (_Float16)W_in[(256 + k) * 256 + n];
    return;
  }
  i -= 65536;
  if (i < 8192) {    // rbf rows 512..531 + d row 532, K padded 20+1 -> 32
    int j = i & 7, lane = (i >> 3) & 63, nt = (i >> 9) & 15;
    int k = (lane >> 4) * 8 + j, n = nt * 16 + (lane & 15);
    float v = 0.0f;
    if (k < 20)       v = W_in[(512 + k) * 256 + n];
    else if (k == 20) v = W_in[532 * 256 + n];
    wpr[i] = (_Float16)v;
    return;
  }
  i -= 8192;
  if (i < 8192) out[i] = b_out[0];
}

// ---------------------------------------------------------------------------
// AP/BP: M=8192 atoms, K=256, N=256, fp16 packed output. BM=64 atoms/block,
// 4 waves (one 64-n slice each). blockIdx.y selects AP (with b_in) or BP.
__global__ __launch_bounds__(256) void k_atoms(
    const _Float16* __restrict__ xh,
    const _Float16* __restrict__ wpi, const _Float16* __restrict__ wpj,
    const float* __restrict__ b_in,
    _Float16* __restrict__ AP, _Float16* __restrict__ BP)
{
  const int tid = threadIdx.x;
  const int l = tid & 63, w = tid >> 6;
  const int g = l >> 4, c = l & 15;
  const int which = blockIdx.y;
  const _Float16* wpx = which ? wpj : wpi;
  _Float16* outp = which ? BP : AP;
  const int abase = blockIdx.x * 64;

  f32x4 acc[4][4];
#pragma unroll
  for (int nf = 0; nf < 4; ++nf)
#pragma unroll
    for (int at = 0; at < 4; ++at) acc[nf][at] = (f32x4)0.0f;

#pragma unroll
  for (int ks = 0; ks < 8; ++ks) {
    f16x8 a[4];
#pragma unroll
    for (int nf = 0; nf < 4; ++nf) {
      H8 t; t.u = *(const u32x4*)(wpx + (((w * 4 + nf) * 8 + ks) * 64 + l) * 8);
      a[nf] = t.v;
    }
#pragma unroll
    for (int at = 0; at < 4; ++at) {
      H8 b; b.u = *(const u32x4*)(xh + (abase + at * 16 + c) * 256 + ks * 32 + g * 8);
#pragma unroll
      for (int nf = 0; nf < 4; ++nf)
        acc[nf][at] = MFMA16(a[nf], b.v, acc[nf][at]);
    }
  }

#pragma unroll
  for (int nf = 0; nf < 4; ++nf) {
    const int n = w * 64 + nf * 16 + g * 4;
    f32x4 bias = (f32x4)0.0f;
    if (!which) bias = *(const f32x4*)(b_in + n);
#pragma unroll
    for (int at = 0; at < 4; ++at) {
      const int atom = abase + at * 16 + c;
      const f32x4 t = acc[nf][at] + bias;
      H2 lo, hi;
      lo.h = __builtin_amdgcn_cvt_pkrtz(t[0], t[1]);
      hi.h = __builtin_amdgcn_cvt_pkrtz(t[2], t[3]);
      u32x2 q; q[0] = lo.u; q[1] = hi.u;
      *(u32x2*)(outp + atom * 256 + n) = q;
    }
  }
}

// ---------------------------------------------------------------------------
// Fused edge pipeline. 128 edges/block, 256 threads = 4 waves; wave w owns
// feature slice [w*64, w*64+64) for ALL 128 edges. acc[4][8] (128 AGPR).
// h tile [128 edges][256 feat] fp16 single-buffered in LDS (64 KB).
// Row swizzle: addr = el*512 + (o ^ sw), sw = (c<<4)|((c&1)<<8).
// 2 barriers/layer; 2 blocks/CU overlap each other's barrier stalls.
__global__ __launch_bounds__(256, 2) void k_edges(
    const _Float16* __restrict__ AP, const _Float16* __restrict__ BP,
    const int* __restrict__ idx_i, const int* __restrict__ idx_j,
    const float* __restrict__ d_ij,
    const _Float16* __restrict__ wp, const _Float16* __restrict__ wpr,
    const float* __restrict__ bs, const float* __restrict__ W_out,
    float* __restrict__ out)
{
  __shared__ __align__(16) char hb[65536];
  __shared__ float d_lds[128];
  __shared__ int   ii_lds[128];
  __shared__ int   jj_lds[128];
  __shared__ float oacc[128];

  const int tid = threadIdx.x;
  const int l = tid & 63, w = tid >> 6;   // w = feature-group 0..3
  const int g = l >> 4, c = l & 15;
  const int ebase = blockIdx.x * 128;
  const int nb = w * 64;          // wave's feature base (64 features)
  const int sw = (c << 4) | ((c & 1) << 8);  // row swizzle

  if (tid < 128) {
    ii_lds[tid] = idx_i[ebase + tid];
    jj_lds[tid] = idx_j[ebase + tid];
    d_lds[tid]  = d_ij[ebase + tid];
    oacc[tid]   = 0.0f;
  }
  __syncthreads();

  f32x4 acc[4][8];  // [nf][et] : D = h^T tile (64 features x 128 edges)

  // ---- input layer: rbf(20)+d via one K=32 MFMA step ----
  {
    const float STEP = 15.0f / 19.0f;
    const float C2 = (-0.5f / (STEP * STEP)) * LOG2E;
    f16x8 afr[4];
#pragma unroll
    for (int nf = 0; nf < 4; ++nf) {
      H8 t; t.u = *(const u32x4*)(wpr + ((w * 4 + nf) * 64 + l) * 8);
      afr[nf] = t.v;
    }
#pragma unroll
    for (int et = 0; et < 8; ++et) {
      const float d = d_lds[et * 16 + c];
      H8 bb;
#pragma unroll
      for (int j = 0; j < 8; ++j) {
        const int k = g * 8 + j;
        float v = 0.0f;
        if (k < 20)       { const float df = d - (float)k * STEP; v = __builtin_amdgcn_exp2f(C2 * df * df); }
        else if (k == 20) { v = d; }
        bb.h[j] = (_Float16)v;
      }
      const f32x4 z = (f32x4)0.0f;
#pragma unroll
      for (int nf = 0; nf < 4; ++nf)
        acc[nf][et] = MFMA16(afr[nf], bb.v, z);
    }
  }
  // h0 = pack(rbf acc) + AP[idx_i] + BP[idx_j]  (fp16 pk_add) -> hb
#pragma unroll
  for (int nf = 0; nf < 4; ++nf) {
    const int n = nb + nf * 16 + g * 4;
    const int obase = n * 2;
#pragma unroll
    for (int et = 0; et < 8; ++et) {
      const int el = et * 16 + c;
      H4 pa, pb, s;
      pa.u = *(const u32x2*)(AP + ii_lds[el] * 256 + n);
      pb.u = *(const u32x2*)(BP + jj_lds[el] * 256 + n);
      H2 lo, hi;
      lo.h = __builtin_amdgcn_cvt_pkrtz(acc[nf][et][0], acc[nf][et][1]);
      hi.h = __builtin_amdgcn_cvt_pkrtz(acc[nf][et][2], acc[nf][et][3]);
      s.u[0] = lo.u; s.u[1] = hi.u;
      s.v = s.v + pa.v + pb.v;
      *(u32x2*)(hb + el * 512 + (obase ^ sw)) = s.u;
    }
  }
  __syncthreads();

  // one fused hidden-layer matmul: acc = bias + (h_lds @ W)^T
  auto mfma_layer = [&](const _Float16* wl, const float* brow) {
#pragma unroll
    for (int nf = 0; nf < 4; ++nf) {
      const f32x4 bias = *(const f32x4*)(brow + nb + nf * 16 + g * 4);
#pragma unroll
      for (int et = 0; et < 8; ++et) acc[nf][et] = bias;
    }
    __builtin_amdgcn_s_setprio(1);
#pragma unroll
    for (int ks = 0; ks < 8; ++ks) {
      f16x8 a[4];
#pragma unroll
      for (int nf = 0; nf < 4; ++nf) {
        H8 t; t.u = *(const u32x4*)(wl + (((w * 4 + nf) * 8 + ks) * 64 + l) * 8);
        a[nf] = t.v;
      }
      const int o = (ks * 64 + g * 16) ^ sw;
#pragma unroll
      for (int et = 0; et < 8; ++et) {
        const int el = et * 16 + c;
        H8 b; b.u = *(const u32x4*)(hb + el * 512 + o);
#pragma unroll
        for (int nf = 0; nf < 4; ++nf)
          acc[nf][et] = MFMA16(a[nf], b.v, acc[nf][et]);
      }
    }
    __builtin_amdgcn_s_setprio(0);
  };

#pragma unroll 1
  for (int ly = 0; ly < 5; ++ly) {
    mfma_layer(wp + ly * 65536, bs + ly * 256);
    __syncthreads();   // all reads of hb done before in-place overwrite
#pragma unroll
    for (int nf = 0; nf < 4; ++nf) {
      const int n = nb + nf * 16 + g * 4;
      const int obase = n * 2;
#pragma unroll
      for (int et = 0; et < 8; ++et) {
        f32x4 v = acc[nf][et];
#pragma unroll
        for (int j = 0; j < 4; ++j) {
          const float e = __builtin_amdgcn_exp2f(v[j] * -LOG2E);
          v[j] = v[j] * __builtin_amdgcn_rcpf(1.0f + e);   // fast SiLU
        }
        const int el = et * 16 + c;
        H2 lo, hi;
        lo.h = __builtin_amdgcn_cvt_pkrtz(v[0], v[1]);
        hi.h = __builtin_amdgcn_cvt_pkrtz(v[2], v[3]);
        u32x2 q; q[0] = lo.u; q[1] = hi.u;
        *(u32x2*)(hb + el * 512 + (obase ^ sw)) = q;
      }
    }
    __syncthreads();   // writes complete before next layer reads
  }

  // layer 6 (no activation): bias already seeded; fold W_out dot immediately
  mfma_layer(wp + 5 * 65536, bs + 5 * 256);
  float sum[8];
#pragma unroll
  for (int et = 0; et < 8; ++et) sum[et] = 0.0f;
#pragma unroll
  for (int nf = 0; nf < 4; ++nf) {
    const int n = nb + nf * 16 + g * 4;
    const f32x4 wo = *(const f32x4*)(W_out + n);
#pragma unroll
    for (int et = 0; et < 8; ++et) {
      const f32x4 v = acc[nf][et];
      sum[et] += v[0] * wo[0] + v[1] * wo[1] + v[2] * wo[2] + v[3] * wo[3];
    }
  }
#pragma unroll
  for (int et = 0; et < 8; ++et) {
    float s = sum[et];
    s += __shfl_xor(s, 16, 64);
    s += __shfl_xor(s, 32, 64);
    if (l < 16) atomicAdd(&oacc[et * 16 + l], s);
  }
  __syncthreads();
  if (tid < 128) atomicAdd(out + ii_lds[tid], oacc[tid]);
}

// ---------------------------------------------------------------------------
extern "C" void kernel_launch(void* const* d_in, const int* in_sizes, int n_in,
                              void* d_out, int out_size, void* d_ws, size_t ws_size,
                              hipStream_t stream) {
  (void)in_sizes; (void)n_in; (void)out_size; (void)ws_size;
  const float* x     = (const float*)d_in[0];
  const float* d_ij  = (const float*)d_in[1];
  const int*   idx_i = (const int*)d_in[2];
  const int*   idx_j = (const int*)d_in[3];
  const float* W_in  = (const float*)d_in[4];
  const float* b_in  = (const float*)d_in[5];
  const float* Ws    = (const float*)d_in[6];
  const float* bs    = (const float*)d_in[7];
  const float* W_out = (const float*)d_in[8];
  const float* b_out = (const float*)d_in[9];
  float* out = (float*)d_out;
  char* ws = (char*)d_ws;

  _Float16* wp  = (_Float16*)(ws + WS_WP);
  _Float16* wpi = (_Float16*)(ws + WS_WPI);
  _Float16* wpj = (_Float16*)(ws + WS_WPJ);
  _Float16* wpr = (_Float16*)(ws + WS_WPR);
  _Float16* xh  = (_Float16*)(ws + WS_XH);
  _Float16* AP  = (_Float16*)(ws + WS_AP);
  _Float16* BP  = (_Float16*)(ws + WS_BP);

  hipLaunchKernelGGL(k_prep, dim3(10305), dim3(256), 0, stream,
                     x, W_in, Ws, b_out, wp, wpi, wpj, wpr, xh, out);
  hipLaunchKernelGGL(k_atoms, dim3(128, 2), dim3(256), 0, stream,
                     xh, wpi, wpj, b_in, AP, BP);
  hipLaunchKernelGGL(k_edges, dim3(2048), dim3(256), 0, stream,
                     AP, BP, idx_i, idx_j, d_ij, wp, wpr, bs, W_out, out);
}